// Round 4
// baseline (234.841 us; speedup 1.0000x reference)
//
#include <hip/hip_runtime.h>
#include <hip/hip_bf16.h>

constexpr int Bb = 8, Ls = 2048, Dd = 512, Rr = 512;
constexpr int M1 = Bb * Ls;  // 16384

typedef _Float16 h8v __attribute__((ext_vector_type(8)));  // 8 fp16 (4 VGPRs)
typedef _Float16 h4v __attribute__((ext_vector_type(4)));  // 4 fp16 (8 B)
typedef float f4v __attribute__((ext_vector_type(4)));     // 4 fp32

__device__ __forceinline__ void async_copy16(const void* g, void* l) {
  __builtin_amdgcn_global_load_lds((const __attribute__((address_space(1))) unsigned int*)g,
                                   (__attribute__((address_space(3))) unsigned int*)l, 16, 0, 0);
}

// XCD-aware swizzle: bijective remap of the flattened grid so the gridDim.x
// blocks sharing one A-strip get hw ids congruent mod 8 -> same XCD's L2.
// Requires (total/8) % gridDim.x-compatible sizes: all our grids have
// (gridDim.y*gridDim.z) % 8 == 0.
__device__ __forceinline__ void swizzle_xy(int& x, int& yy) {
  const int NX = gridDim.x;
  const int lin = ((int)blockIdx.z * (int)gridDim.y + (int)blockIdx.y) * NX + (int)blockIdx.x;
  const int xcd = lin & 7;
  const int w = lin >> 3;
  x = w % NX;
  yy = (w / NX) * 8 + xcd;
}

// ---------------------------------------------------------------------------
// cvt_query: query (B,L,D) fp32 -> qs fp16 (B,L,D) and qt fp16 (B,D,L).
// ---------------------------------------------------------------------------
__global__ __launch_bounds__(256) void cvt_query(const float* __restrict__ q,
                                                 _Float16* __restrict__ qs,
                                                 _Float16* __restrict__ qt) {
  __shared__ float t[64][65];
  const int b = blockIdx.z, l0 = blockIdx.y * 64, d0 = blockIdx.x * 64;
  const int tid = threadIdx.x;
  const int r = tid >> 4, c4 = (tid & 15) * 4;
#pragma unroll
  for (int i = 0; i < 4; ++i) {
    const int l = r + i * 16;
    const float4 v = *(const float4*)&q[((long)b * Ls + l0 + l) * Dd + d0 + c4];
    t[l][c4] = v.x; t[l][c4 + 1] = v.y; t[l][c4 + 2] = v.z; t[l][c4 + 3] = v.w;
    h4v h = {(_Float16)v.x, (_Float16)v.y, (_Float16)v.z, (_Float16)v.w};
    *(h4v*)&qs[((long)b * Ls + l0 + l) * Dd + d0 + c4] = h;
  }
  __syncthreads();
#pragma unroll
  for (int i = 0; i < 4; ++i) {
    const int d = r + i * 16;
    h4v h = {(_Float16)t[c4][d], (_Float16)t[c4 + 1][d],
             (_Float16)t[c4 + 2][d], (_Float16)t[c4 + 3][d]};
    *(h4v*)&qt[((long)b * Dd + d0 + d) * Ls + l0 + c4] = h;
  }
}

__global__ __launch_bounds__(256) void cvt_mat(const float* __restrict__ a,
                                               _Float16* __restrict__ h, int n4) {
  int i = blockIdx.x * 256 + threadIdx.x;
  if (i < n4) {
    float4 v = *(const float4*)&a[i * 4];
    h4v o = {(_Float16)v.x, (_Float16)v.y, (_Float16)v.z, (_Float16)v.w};
    *(h4v*)&h[i * 4] = o;
  }
}

// cq16[i] = fp16(cq32[i] + bc[i % 512])
__global__ __launch_bounds__(256) void cvt_cq(const float* __restrict__ s,
                                              const float* __restrict__ bc,
                                              _Float16* __restrict__ d, int n4) {
  int i = blockIdx.x * 256 + threadIdx.x;
  if (i < n4) {
    float4 v = *(const float4*)&s[(long)i * 4];
    int c = (i * 4) & 511;
    h4v o = {(_Float16)(v.x + bc[c]), (_Float16)(v.y + bc[c + 1]),
             (_Float16)(v.z + bc[c + 2]), (_Float16)(v.w + bc[c + 3])};
    *(h4v*)&d[(long)i * 4] = o;
  }
}

// ---------------------------------------------------------------------------
// build_bz: Bz[r,0:512]=1/w^2 ; Bz[r,512:1024]=-2*c/w^2 (fp16); cc[r]=sum c^2/w^2
// ---------------------------------------------------------------------------
__global__ __launch_bounds__(256) void build_bz(const float* __restrict__ centers,
                                                const float* __restrict__ widths,
                                                _Float16* __restrict__ bz,
                                                float* __restrict__ cc) {
  const int wave = threadIdx.x >> 6, lane = threadIdx.x & 63;
  const int r = blockIdx.x * 4 + wave;
  float s = 0.f;
#pragma unroll
  for (int j = 0; j < 8; ++j) {
    int d = j * 64 + lane;
    float c = centers[(long)r * Dd + d];
    float w = widths[(long)r * Dd + d];
    float iw = 1.0f / (w * w);
    bz[(long)r * 1024 + d] = (_Float16)iw;
    bz[(long)r * 1024 + 512 + d] = (_Float16)(-2.0f * c * iw);
    s += c * c * iw;
  }
#pragma unroll
  for (int o = 32; o > 0; o >>= 1) s += __shfl_xor(s, o, 64);
  if (lane == 0) cc[r] = s;
}

// ---------------------------------------------------------------------------
// fp16 MFMA GEMM: C = A * B^T (+epilogue). A: M x K (row stride ldA),
// B: N x K (row stride ldB), fp16 K-major. Block tile (AI*32) x 128, BK=32,
// 256 threads = 4 waves (2x2). Swizzled grid; z-dim = batch (sA/sB/sC) or
// split-K slice (kstep).
// EPI: 0 = q-GEMM (qv=acc+bias[n]; Az: col n <- qv^2, col 512+n <- qv)
//      3 = out    (Cf = acc)
//      4 = splitK (unsafeAtomicAdd(Cf, acc))
// ---------------------------------------------------------------------------
template <int AI, int EPI>
__global__ __launch_bounds__(256) void gemm_h(
    const _Float16* __restrict__ A, const _Float16* __restrict__ Bm,
    const float* __restrict__ bias, float* __restrict__ Cf,
    _Float16* __restrict__ Ch, int Kext, int ldA, int ldB, int ldC, int kstep,
    long sA, long sB, long sC) {
  constexpr int TM = AI * 32;
  __shared__ _Float16 As[TM * 32];
  __shared__ _Float16 Bs[128 * 32];
  int x, yy;
  swizzle_xy(x, yy);
  const int y = yy % (int)gridDim.y;
  const int zz = yy / (int)gridDim.y;
  const int n0 = x * 128;
  const int m0 = y * TM;
  const int kb = zz * kstep;
  const _Float16* Ab = A + (long)zz * sA;
  const _Float16* Bb = Bm + (long)zz * sB;

  const int tid = threadIdx.x;
  const int wave = tid >> 6, lane = tid & 63;
  const int wm = wave >> 1, wn = wave & 1;
  const int quad = lane >> 4, tr = lane & 15;
  const int lrow = lane >> 2;        // 0..15 row within a 16-row chunk
  const int lcol = (lane & 3) * 8;   // fp16 element offset of lane's 16B

  f4v acc[AI][4];
#pragma unroll
  for (int i = 0; i < AI; ++i)
#pragma unroll
    for (int j = 0; j < 4; ++j) acc[i][j] = (f4v){0.f, 0.f, 0.f, 0.f};

  for (int k0 = 0; k0 < Kext; k0 += 32) {
    __syncthreads();
#pragma unroll
    for (int c = wave; c < TM / 16; c += 4) {
      const long g = (long)(m0 + c * 16 + lrow) * ldA + kb + k0 + lcol;
      async_copy16(Ab + g, As + c * 512);
    }
#pragma unroll
    for (int c = wave; c < 8; c += 4) {
      const long g = (long)(n0 + c * 16 + lrow) * ldB + kb + k0 + lcol;
      async_copy16(Bb + g, Bs + c * 512);
    }
    __syncthreads();

    h8v af[AI], bf[4];
#pragma unroll
    for (int i = 0; i < AI; ++i)
      af[i] = *(const h8v*)&As[(wm * (AI * 16) + i * 16 + tr) * 32 + quad * 8];
#pragma unroll
    for (int j = 0; j < 4; ++j)
      bf[j] = *(const h8v*)&Bs[(wn * 64 + j * 16 + tr) * 32 + quad * 8];
#pragma unroll
    for (int i = 0; i < AI; ++i)
#pragma unroll
      for (int j = 0; j < 4; ++j)
        acc[i][j] = __builtin_amdgcn_mfma_f32_16x16x32_f16(af[i], bf[j], acc[i][j], 0, 0, 0);
  }

  float* Cfb = Cf ? Cf + (long)zz * sC : nullptr;
  _Float16* Chb = Ch ? Ch + (long)zz * sC : nullptr;
#pragma unroll
  for (int i = 0; i < AI; ++i)
#pragma unroll
    for (int j = 0; j < 4; ++j) {
      const int rbase = m0 + wm * (AI * 16) + i * 16 + quad * 4;
      const int cg = n0 + wn * 64 + j * 16 + tr;
#pragma unroll
      for (int r = 0; r < 4; ++r) {
        const float v = acc[i][j][r];
        const long row = rbase + r;
        if (EPI == 0) {
          const float qv = v + bias[cg];
          Chb[row * (long)ldC + cg] = (_Float16)(qv * qv);
          Chb[row * (long)ldC + 512 + cg] = (_Float16)qv;
        } else if (EPI == 3) {
          Cfb[row * (long)ldC + cg] = v;
        } else if (EPI == 4) {
          unsafeAtomicAdd(&Cfb[row * (long)ldC + cg], v);
        }
      }
    }
}

// ---------------------------------------------------------------------------
// Fused z-GEMM + softmax: each block computes 64 full rows of
// z = -(Az @ Bz^T + cc)/1024 (K=1024, N=512), softmaxes them, writes Fss fp16.
// 4 waves side-by-side in N (each 64 rows x 128 cols, acc[4][8]).
// ---------------------------------------------------------------------------
__global__ __launch_bounds__(256, 2) void z_softmax(
    const _Float16* __restrict__ Az, const _Float16* __restrict__ Bz,
    const float* __restrict__ cc, _Float16* __restrict__ F) {
  __shared__ _Float16 As[64 * 32];    // 4 KB
  __shared__ _Float16 Bs[512 * 32];   // 32 KB
  __shared__ float red[2][4][64];     // 2 KB
  const int m0 = blockIdx.x * 64;
  const int tid = threadIdx.x, wave = tid >> 6, lane = tid & 63;
  const int quad = lane >> 4, tr = lane & 15;
  const int lrow = lane >> 2, lcol = (lane & 3) * 8;
  const int nb = wave * 128;

  f4v acc[4][8];
#pragma unroll
  for (int i = 0; i < 4; ++i)
#pragma unroll
    for (int j = 0; j < 8; ++j) acc[i][j] = (f4v){0.f, 0.f, 0.f, 0.f};

  for (int k0 = 0; k0 < 1024; k0 += 32) {
    __syncthreads();
    {  // A: 64 rows = 4 chunks; wave w stages chunk w
      const long g = (long)(m0 + wave * 16 + lrow) * 1024 + k0 + lcol;
      async_copy16(Az + g, As + wave * 512);
    }
#pragma unroll
    for (int c = wave; c < 32; c += 4) {  // B: 512 rows = 32 chunks
      const long g = (long)(c * 16 + lrow) * 1024 + k0 + lcol;
      async_copy16(Bz + g, Bs + c * 512);
    }
    __syncthreads();

    h8v af[4], bf[8];
#pragma unroll
    for (int i = 0; i < 4; ++i) af[i] = *(const h8v*)&As[(i * 16 + tr) * 32 + quad * 8];
#pragma unroll
    for (int j = 0; j < 8; ++j) bf[j] = *(const h8v*)&Bs[(nb + j * 16 + tr) * 32 + quad * 8];
#pragma unroll
    for (int i = 0; i < 4; ++i)
#pragma unroll
      for (int j = 0; j < 8; ++j)
        acc[i][j] = __builtin_amdgcn_mfma_f32_16x16x32_f16(af[i], bf[j], acc[i][j], 0, 0, 0);
  }

  // z = (acc + cc[col]) * (-1/1024); per-row softmax across all 512 cols.
  float ccv[8];
#pragma unroll
  for (int j = 0; j < 8; ++j) ccv[j] = cc[nb + j * 16 + tr];
  constexpr float zs = -0.0009765625f;
  float mx[4][4];
#pragma unroll
  for (int i = 0; i < 4; ++i)
#pragma unroll
    for (int r = 0; r < 4; ++r) {
      float m = -1e30f;
#pragma unroll
      for (int j = 0; j < 8; ++j) {
        const float zv = (acc[i][j][r] + ccv[j]) * zs;
        acc[i][j][r] = zv;
        m = fmaxf(m, zv);
      }
      mx[i][r] = m;
    }
#pragma unroll
  for (int o = 1; o < 16; o <<= 1)
#pragma unroll
    for (int i = 0; i < 4; ++i)
#pragma unroll
      for (int r = 0; r < 4; ++r) mx[i][r] = fmaxf(mx[i][r], __shfl_xor(mx[i][r], o, 64));
  if (tr == 0)
#pragma unroll
    for (int i = 0; i < 4; ++i)
#pragma unroll
      for (int r = 0; r < 4; ++r) red[0][wave][i * 16 + quad * 4 + r] = mx[i][r];
  __syncthreads();
  float sm[4][4];
#pragma unroll
  for (int i = 0; i < 4; ++i)
#pragma unroll
    for (int r = 0; r < 4; ++r) {
      const int rl = i * 16 + quad * 4 + r;
      const float m = fmaxf(fmaxf(red[0][0][rl], red[0][1][rl]),
                            fmaxf(red[0][2][rl], red[0][3][rl]));
      mx[i][r] = m;
      float s = 0.f;
#pragma unroll
      for (int j = 0; j < 8; ++j) {
        const float e = __expf(acc[i][j][r] - m);
        acc[i][j][r] = e;
        s += e;
      }
      sm[i][r] = s;
    }
#pragma unroll
  for (int o = 1; o < 16; o <<= 1)
#pragma unroll
    for (int i = 0; i < 4; ++i)
#pragma unroll
      for (int r = 0; r < 4; ++r) sm[i][r] += __shfl_xor(sm[i][r], o, 64);
  if (tr == 0)
#pragma unroll
    for (int i = 0; i < 4; ++i)
#pragma unroll
      for (int r = 0; r < 4; ++r) red[1][wave][i * 16 + quad * 4 + r] = sm[i][r];
  __syncthreads();
#pragma unroll
  for (int i = 0; i < 4; ++i)
#pragma unroll
    for (int r = 0; r < 4; ++r) {
      const int rl = i * 16 + quad * 4 + r;
      const float inv = 1.0f / (red[1][0][rl] + red[1][1][rl] + red[1][2][rl] + red[1][3][rl]);
      const long rowoff = (long)(m0 + rl) * 512 + nb;
#pragma unroll
      for (int j = 0; j < 8; ++j)
        F[rowoff + j * 16 + tr] = (_Float16)(acc[i][j][r] * inv);
    }
}

// ---------------------------------------------------------------------------
extern "C" void kernel_launch(void* const* d_in, const int* in_sizes, int n_in,
                              void* d_out, int out_size, void* d_ws, size_t ws_size,
                              hipStream_t stream) {
  const float* query   = (const float*)d_in[0];
  const float* Wq      = (const float*)d_in[1];
  const float* bq      = (const float*)d_in[2];
  const float* Wc      = (const float*)d_in[3];
  const float* bc      = (const float*)d_in[4];
  const float* centers = (const float*)d_in[5];
  const float* widths  = (const float*)d_in[6];
  float* out = (float*)d_out;

  char* base = (char*)d_ws;
  auto alloc = [&](size_t bytes) {
    char* p = base;
    base += (bytes + 255) & ~(size_t)255;
    return p;
  };
  _Float16* qs  = (_Float16*)alloc((size_t)M1 * Dd * 2);      // 16.8 MB
  _Float16* qt  = (_Float16*)alloc((size_t)M1 * Dd * 2);      // 16.8 MB (B,D,L)
  _Float16* az  = (_Float16*)alloc((size_t)M1 * 1024 * 2);    // 33.6 MB
  _Float16* fs  = (_Float16*)alloc((size_t)M1 * Rr * 2);      // 16.8 MB
  _Float16* wq  = (_Float16*)alloc((size_t)Dd * Dd * 2);
  _Float16* wc  = (_Float16*)alloc((size_t)Rr * Ls * 2);
  _Float16* bzm = (_Float16*)alloc((size_t)Rr * 1024 * 2);
  float*    cc  = (float*)alloc((size_t)Rr * 4);
  float*    cq32 = (float*)alloc((size_t)Bb * Dd * Rr * 4);   // 8.4 MB
  _Float16* cq  = (_Float16*)alloc((size_t)Bb * Dd * Rr * 2); // 4.2 MB

  // conversions / precompute
  cvt_query<<<dim3(Dd / 64, Ls / 64, Bb), 256, 0, stream>>>(query, qs, qt);
  cvt_mat<<<(Dd * Dd / 4 + 255) / 256, 256, 0, stream>>>(Wq, wq, Dd * Dd / 4);
  cvt_mat<<<(Rr * Ls / 4 + 255) / 256, 256, 0, stream>>>(Wc, wc, Rr * Ls / 4);
  build_bz<<<Rr / 4, 256, 0, stream>>>(centers, widths, bzm, cc);
  hipMemsetAsync(cq32, 0, (size_t)Bb * Dd * Rr * 4, stream);

  // q-GEMM: q = query @ Wq^T + bq; epilogue writes Az = [q^2, q] fp16
  gemm_h<4, 0><<<dim3(Dd / 128, M1 / 128, 1), 256, 0, stream>>>(
      qs, wq, bq, nullptr, az, Dd, Dd, Dd, 1024, 0, 0, 0, 0);

  // fused z-GEMM + softmax -> Fss fp16
  z_softmax<<<M1 / 64, 256, 0, stream>>>(az, bzm, cc, fs);

  // conqT split-K=4: cq32[(b,d), r] += qt[(b,d), ks:ks+512] . Wc[r, ks:ks+512]
  gemm_h<2, 4><<<dim3(Rr / 128, (Bb * Dd) / 64, 4), 256, 0, stream>>>(
      qt, wc, nullptr, cq32, nullptr, 512, Ls, Ls, Rr, 512, 0, 0, 0);
  cvt_cq<<<(Bb * Dd * Rr / 4 + 255) / 256, 256, 0, stream>>>(
      cq32, bc, cq, Bb * Dd * Rr / 4);

  // out-GEMM: out[b] = Fss[b] @ cq[b]^T
  gemm_h<4, 3><<<dim3(Dd / 128, Ls / 128, Bb), 256, 0, stream>>>(
      fs, cq, nullptr, out, nullptr, Rr, Rr, Rr, Dd, 0,
      (long)Ls * Rr, (long)Dd * Rr, (long)Ls * Dd);
}

// Round 5
// 212.328 us; speedup vs baseline: 1.1060x; 1.1060x over previous
//
#include <hip/hip_runtime.h>
#include <hip/hip_bf16.h>

constexpr int Bb = 8, Ls = 2048, Dd = 512, Rr = 512;
constexpr int M1 = Bb * Ls;  // 16384

typedef _Float16 h8v __attribute__((ext_vector_type(8)));  // 8 fp16 (4 VGPRs)
typedef _Float16 h4v __attribute__((ext_vector_type(4)));  // 4 fp16 (8 B)
typedef float f4v __attribute__((ext_vector_type(4)));     // 4 fp32

__device__ __forceinline__ void async_copy16(const void* g, void* l) {
  __builtin_amdgcn_global_load_lds((const __attribute__((address_space(1))) unsigned int*)g,
                                   (__attribute__((address_space(3))) unsigned int*)l, 16, 0, 0);
}

// XCD-aware swizzle: blocks sharing an A-strip (same y) land 8 apart in the
// flattened hw id -> same XCD's L2. Bijective; requires gy*gz % 8 == 0.
__device__ __forceinline__ void swizzle_xy(int& x, int& yy) {
  const int NX = gridDim.x;
  const int lin = ((int)blockIdx.z * (int)gridDim.y + (int)blockIdx.y) * NX + (int)blockIdx.x;
  const int xcd = lin & 7;
  const int w = lin >> 3;
  x = w % NX;
  yy = (w / NX) * 8 + xcd;
}

// ---------------------------------------------------------------------------
// cvt_query: query (B,L,D) fp32 -> qs fp16 (B,L,D) and qt fp16 (B,D,L).
// ---------------------------------------------------------------------------
__global__ __launch_bounds__(256) void cvt_query(const float* __restrict__ q,
                                                 _Float16* __restrict__ qs,
                                                 _Float16* __restrict__ qt) {
  __shared__ float t[64][65];
  const int b = blockIdx.z, l0 = blockIdx.y * 64, d0 = blockIdx.x * 64;
  const int tid = threadIdx.x;
  const int r = tid >> 4, c4 = (tid & 15) * 4;
#pragma unroll
  for (int i = 0; i < 4; ++i) {
    const int l = r + i * 16;
    const float4 v = *(const float4*)&q[((long)b * Ls + l0 + l) * Dd + d0 + c4];
    t[l][c4] = v.x; t[l][c4 + 1] = v.y; t[l][c4 + 2] = v.z; t[l][c4 + 3] = v.w;
    h4v h = {(_Float16)v.x, (_Float16)v.y, (_Float16)v.z, (_Float16)v.w};
    *(h4v*)&qs[((long)b * Ls + l0 + l) * Dd + d0 + c4] = h;
  }
  __syncthreads();
#pragma unroll
  for (int i = 0; i < 4; ++i) {
    const int d = r + i * 16;
    h4v h = {(_Float16)t[c4][d], (_Float16)t[c4 + 1][d],
             (_Float16)t[c4 + 2][d], (_Float16)t[c4 + 3][d]};
    *(h4v*)&qt[((long)b * Dd + d0 + d) * Ls + l0 + c4] = h;
  }
}

// ---------------------------------------------------------------------------
// prep: one launch for (a) Wq fp32->fp16, (b) Wc fp32->fp16,
// (c) iw = 1/w^2, c2 = -2c/w^2 (fp16, 512-col rows) + cc[r] = sum c^2/w^2.
// Blocks: [0,256) Wq ; [256,1280) Wc ; [1280,1408) fuzzy params.
// ---------------------------------------------------------------------------
__global__ __launch_bounds__(256) void prep(
    const float* __restrict__ Wq, _Float16* __restrict__ wq,
    const float* __restrict__ Wc, _Float16* __restrict__ wc,
    const float* __restrict__ centers, const float* __restrict__ widths,
    _Float16* __restrict__ iwh, _Float16* __restrict__ c2h,
    float* __restrict__ cc) {
  const int bid = blockIdx.x, tid = threadIdx.x;
  if (bid < 256) {
    const int i = bid * 256 + tid;
    float4 v = *(const float4*)&Wq[(long)i * 4];
    h4v o = {(_Float16)v.x, (_Float16)v.y, (_Float16)v.z, (_Float16)v.w};
    *(h4v*)&wq[(long)i * 4] = o;
  } else if (bid < 1280) {
    const int i = (bid - 256) * 256 + tid;
    float4 v = *(const float4*)&Wc[(long)i * 4];
    h4v o = {(_Float16)v.x, (_Float16)v.y, (_Float16)v.z, (_Float16)v.w};
    *(h4v*)&wc[(long)i * 4] = o;
  } else {
    const int wave = tid >> 6, lane = tid & 63;
    const int r = (bid - 1280) * 4 + wave;
    float s = 0.f;
#pragma unroll
    for (int j = 0; j < 8; ++j) {
      const int d = j * 64 + lane;
      const float c = centers[(long)r * Dd + d];
      const float w = widths[(long)r * Dd + d];
      const float iw = 1.0f / (w * w);
      iwh[(long)r * Dd + d] = (_Float16)iw;
      c2h[(long)r * Dd + d] = (_Float16)(-2.0f * c * iw);
      s += c * c * iw;
    }
#pragma unroll
    for (int o = 32; o > 0; o >>= 1) s += __shfl_xor(s, o, 64);
    if (lane == 0) cc[r] = s;
  }
}

// cq16[i] = fp16(cq32[i] + bc[i % 512])
__global__ __launch_bounds__(256) void cvt_cq(const float* __restrict__ s,
                                              const float* __restrict__ bc,
                                              _Float16* __restrict__ d, int n4) {
  int i = blockIdx.x * 256 + threadIdx.x;
  if (i < n4) {
    float4 v = *(const float4*)&s[(long)i * 4];
    int c = (i * 4) & 511;
    h4v o = {(_Float16)(v.x + bc[c]), (_Float16)(v.y + bc[c + 1]),
             (_Float16)(v.z + bc[c + 2]), (_Float16)(v.w + bc[c + 3])};
    *(h4v*)&d[(long)i * 4] = o;
  }
}

// ---------------------------------------------------------------------------
// fp16 MFMA GEMM: C = A * B^T. A: M x K (row stride ldA), B: N x K (ldB).
// Block tile (AI*32) x 128, BK=32, 256 threads = 4 waves (2x2). Swizzled.
// EPI: 2 = fp16 out with bias   (Ch = fp16(acc + bias[n]))
//      3 = fp32 out             (Cf = acc)
//      4 = split-K atomic       (unsafeAtomicAdd(Cf, acc))
// ---------------------------------------------------------------------------
template <int AI, int EPI>
__global__ __launch_bounds__(256) void gemm_h(
    const _Float16* __restrict__ A, const _Float16* __restrict__ Bm,
    const float* __restrict__ bias, float* __restrict__ Cf,
    _Float16* __restrict__ Ch, int Kext, int ldA, int ldB, int ldC, int kstep,
    long sA, long sB, long sC) {
  constexpr int TM = AI * 32;
  __shared__ _Float16 As[TM * 32];
  __shared__ _Float16 Bs[128 * 32];
  int x, yy;
  swizzle_xy(x, yy);
  const int y = yy % (int)gridDim.y;
  const int zz = yy / (int)gridDim.y;
  const int n0 = x * 128;
  const int m0 = y * TM;
  const int kb = zz * kstep;
  const _Float16* Ab = A + (long)zz * sA;
  const _Float16* Bb = Bm + (long)zz * sB;

  const int tid = threadIdx.x;
  const int wave = tid >> 6, lane = tid & 63;
  const int wm = wave >> 1, wn = wave & 1;
  const int quad = lane >> 4, tr = lane & 15;
  const int lrow = lane >> 2;
  const int lcol = (lane & 3) * 8;

  f4v acc[AI][4];
#pragma unroll
  for (int i = 0; i < AI; ++i)
#pragma unroll
    for (int j = 0; j < 4; ++j) acc[i][j] = (f4v){0.f, 0.f, 0.f, 0.f};

  for (int k0 = 0; k0 < Kext; k0 += 32) {
    __syncthreads();
#pragma unroll
    for (int c = wave; c < TM / 16; c += 4) {
      const long g = (long)(m0 + c * 16 + lrow) * ldA + kb + k0 + lcol;
      async_copy16(Ab + g, As + c * 512);
    }
#pragma unroll
    for (int c = wave; c < 8; c += 4) {
      const long g = (long)(n0 + c * 16 + lrow) * ldB + kb + k0 + lcol;
      async_copy16(Bb + g, Bs + c * 512);
    }
    __syncthreads();

    h8v af[AI], bf[4];
#pragma unroll
    for (int i = 0; i < AI; ++i)
      af[i] = *(const h8v*)&As[(wm * (AI * 16) + i * 16 + tr) * 32 + quad * 8];
#pragma unroll
    for (int j = 0; j < 4; ++j)
      bf[j] = *(const h8v*)&Bs[(wn * 64 + j * 16 + tr) * 32 + quad * 8];
#pragma unroll
    for (int i = 0; i < AI; ++i)
#pragma unroll
      for (int j = 0; j < 4; ++j)
        acc[i][j] = __builtin_amdgcn_mfma_f32_16x16x32_f16(af[i], bf[j], acc[i][j], 0, 0, 0);
  }

  float* Cfb = Cf ? Cf + (long)zz * sC : nullptr;
  _Float16* Chb = Ch ? Ch + (long)zz * sC : nullptr;
#pragma unroll
  for (int i = 0; i < AI; ++i)
#pragma unroll
    for (int j = 0; j < 4; ++j) {
      const int rbase = m0 + wm * (AI * 16) + i * 16 + quad * 4;
      const int cg = n0 + wn * 64 + j * 16 + tr;
#pragma unroll
      for (int r = 0; r < 4; ++r) {
        const float v = acc[i][j][r];
        const long row = rbase + r;
        if (EPI == 2) {
          Chb[row * (long)ldC + cg] = (_Float16)(v + bias[cg]);
        } else if (EPI == 3) {
          Cfb[row * (long)ldC + cg] = v;
        } else if (EPI == 4) {
          unsafeAtomicAdd(&Cfb[row * (long)ldC + cg], v);
        }
      }
    }
}

// ---------------------------------------------------------------------------
// zq_gemm: z[m,n] = -(1/1024) * ( sum_k q^2[m,k]*iw[n,k] + q[m,k]*c2[n,k]
//                                 + cc[n] ),  K = 512.
// A-fragments squared IN REGISTERS (v_pk_mul_f16) -> no az buffer, no extra
// barrier. 128x128 tile, grid (4, 128) swizzled, 24 KB LDS.
// ---------------------------------------------------------------------------
__global__ __launch_bounds__(256) void zq_gemm(
    const _Float16* __restrict__ Q, const _Float16* __restrict__ Iw,
    const _Float16* __restrict__ C2, const float* __restrict__ cc,
    float* __restrict__ Z) {
  __shared__ _Float16 As[128 * 32];   // 8 KB
  __shared__ _Float16 B1[128 * 32];   // 8 KB (iw)
  __shared__ _Float16 B2[128 * 32];   // 8 KB (-2c*iw)
  int x, yy;
  swizzle_xy(x, yy);
  const int n0 = x * 128;
  const int m0 = yy * 128;

  const int tid = threadIdx.x;
  const int wave = tid >> 6, lane = tid & 63;
  const int wm = wave >> 1, wn = wave & 1;
  const int quad = lane >> 4, tr = lane & 15;
  const int lrow = lane >> 2;
  const int lcol = (lane & 3) * 8;

  f4v acc[4][4];
#pragma unroll
  for (int i = 0; i < 4; ++i)
#pragma unroll
    for (int j = 0; j < 4; ++j) acc[i][j] = (f4v){0.f, 0.f, 0.f, 0.f};

  for (int k0 = 0; k0 < 512; k0 += 32) {
    __syncthreads();
#pragma unroll
    for (int c = wave; c < 8; c += 4) {
      const long ga = (long)(m0 + c * 16 + lrow) * 512 + k0 + lcol;
      async_copy16(Q + ga, As + c * 512);
      const long gb = (long)(n0 + c * 16 + lrow) * 512 + k0 + lcol;
      async_copy16(Iw + gb, B1 + c * 512);
      async_copy16(C2 + gb, B2 + c * 512);
    }
    __syncthreads();

    h8v af[4], af2[4], b1[4], b2[4];
#pragma unroll
    for (int i = 0; i < 4; ++i) {
      af[i] = *(const h8v*)&As[(wm * 64 + i * 16 + tr) * 32 + quad * 8];
      af2[i] = af[i] * af[i];  // v_pk_mul_f16 x4
    }
#pragma unroll
    for (int j = 0; j < 4; ++j) {
      b1[j] = *(const h8v*)&B1[(wn * 64 + j * 16 + tr) * 32 + quad * 8];
      b2[j] = *(const h8v*)&B2[(wn * 64 + j * 16 + tr) * 32 + quad * 8];
    }
#pragma unroll
    for (int i = 0; i < 4; ++i)
#pragma unroll
      for (int j = 0; j < 4; ++j) {
        acc[i][j] = __builtin_amdgcn_mfma_f32_16x16x32_f16(af2[i], b1[j], acc[i][j], 0, 0, 0);
        acc[i][j] = __builtin_amdgcn_mfma_f32_16x16x32_f16(af[i], b2[j], acc[i][j], 0, 0, 0);
      }
  }

  constexpr float zs = -0.0009765625f;  // -(0.5/512)
#pragma unroll
  for (int i = 0; i < 4; ++i)
#pragma unroll
    for (int j = 0; j < 4; ++j) {
      const int rbase = m0 + wm * 64 + i * 16 + quad * 4;
      const int cg = n0 + wn * 64 + j * 16 + tr;
      const float ccv = cc[cg];
#pragma unroll
      for (int r = 0; r < 4; ++r)
        Z[(long)(rbase + r) * 512 + cg] = (acc[i][j][r] + ccv) * zs;
    }
}

// ---------------------------------------------------------------------------
// softmax over R=512: read z fp32, write Fss fp16. One wave per row.
// ---------------------------------------------------------------------------
__global__ __launch_bounds__(256) void softmax_h(const float* __restrict__ Z,
                                                 _Float16* __restrict__ F) {
  const int wave = threadIdx.x >> 6;
  const int lane = threadIdx.x & 63;
  const long row = (long)blockIdx.x * 4 + wave;
  const float* p = Z + row * Rr;
  float4 v0 = *(const float4*)&p[lane * 8];
  float4 v1 = *(const float4*)&p[lane * 8 + 4];
  float v[8] = {v0.x, v0.y, v0.z, v0.w, v1.x, v1.y, v1.z, v1.w};
  float m = v[0];
#pragma unroll
  for (int i = 1; i < 8; ++i) m = fmaxf(m, v[i]);
#pragma unroll
  for (int s = 32; s > 0; s >>= 1) m = fmaxf(m, __shfl_xor(m, s, 64));
  float sum = 0.f;
#pragma unroll
  for (int i = 0; i < 8; ++i) {
    v[i] = __expf(v[i] - m);
    sum += v[i];
  }
#pragma unroll
  for (int s = 32; s > 0; s >>= 1) sum += __shfl_xor(sum, s, 64);
  const float inv = 1.0f / sum;
  h8v o;
#pragma unroll
  for (int i = 0; i < 8; ++i) o[i] = (_Float16)(v[i] * inv);
  *(h8v*)&F[row * Rr + lane * 8] = o;
}

// ---------------------------------------------------------------------------
extern "C" void kernel_launch(void* const* d_in, const int* in_sizes, int n_in,
                              void* d_out, int out_size, void* d_ws, size_t ws_size,
                              hipStream_t stream) {
  const float* query   = (const float*)d_in[0];
  const float* Wq      = (const float*)d_in[1];
  const float* bq      = (const float*)d_in[2];
  const float* Wc      = (const float*)d_in[3];
  const float* bc      = (const float*)d_in[4];
  const float* centers = (const float*)d_in[5];
  const float* widths  = (const float*)d_in[6];
  float* out = (float*)d_out;

  char* base = (char*)d_ws;
  auto alloc = [&](size_t bytes) {
    char* p = base;
    base += (bytes + 255) & ~(size_t)255;
    return p;
  };
  _Float16* qs  = (_Float16*)alloc((size_t)M1 * Dd * 2);      // 16.8 MB
  _Float16* qt  = (_Float16*)alloc((size_t)M1 * Dd * 2);      // 16.8 MB (B,D,L)
  _Float16* q16 = (_Float16*)alloc((size_t)M1 * Dd * 2);      // 16.8 MB
  float*    z   = (float*)alloc((size_t)M1 * Rr * 4);         // 33.6 MB
  _Float16* fs  = (_Float16*)alloc((size_t)M1 * Rr * 2);      // 16.8 MB
  _Float16* wq  = (_Float16*)alloc((size_t)Dd * Dd * 2);
  _Float16* wc  = (_Float16*)alloc((size_t)Rr * Ls * 2);
  _Float16* iwh = (_Float16*)alloc((size_t)Rr * Dd * 2);
  _Float16* c2h = (_Float16*)alloc((size_t)Rr * Dd * 2);
  float*    cc  = (float*)alloc((size_t)Rr * 4);
  float*    cq32 = (float*)alloc((size_t)Bb * Dd * Rr * 4);   // 8.4 MB
  _Float16* cq  = (_Float16*)alloc((size_t)Bb * Dd * Rr * 2); // 4.2 MB

  // conversions / precompute
  cvt_query<<<dim3(Dd / 64, Ls / 64, Bb), 256, 0, stream>>>(query, qs, qt);
  prep<<<1408, 256, 0, stream>>>(Wq, wq, Wc, wc, centers, widths, iwh, c2h, cc);
  hipMemsetAsync(cq32, 0, (size_t)Bb * Dd * Rr * 4, stream);

  // q-GEMM: q16 = fp16(query @ Wq^T + bq)
  gemm_h<4, 2><<<dim3(Dd / 128, M1 / 128, 1), 256, 0, stream>>>(
      qs, wq, bq, nullptr, q16, Dd, Dd, Dd, Dd, 0, 0, 0, 0);

  // z-GEMM with in-register squared A-fragments
  zq_gemm<<<dim3(Rr / 128, M1 / 128, 1), 256, 0, stream>>>(q16, iwh, c2h, cc, z);

  // softmax -> Fss fp16
  softmax_h<<<M1 / 4, 256, 0, stream>>>(z, fs);

  // conq split-K=4: cq32[(b,d), r] += qt[(b,d), ks:ks+512] . Wc[r, ks:ks+512]
  gemm_h<2, 4><<<dim3(Rr / 128, (Bb * Dd) / 64, 4), 256, 0, stream>>>(
      qt, wc, nullptr, cq32, nullptr, 512, Ls, Ls, Rr, 512, 0, 0, 0);
  cvt_cq<<<(Bb * Dd * Rr / 4 + 255) / 256, 256, 0, stream>>>(
      cq32, bc, cq, Bb * Dd * Rr / 4);

  // out-GEMM: out[b] = Fss[b] @ cq[b]^T
  gemm_h<4, 3><<<dim3(Dd / 128, Ls / 128, Bb), 256, 0, stream>>>(
      fs, cq, nullptr, out, nullptr, Rr, Rr, Rr, Dd, 0,
      (long)Ls * Rr, (long)Dd * Rr, (long)Ls * Dd);
}

// Round 6
// 190.084 us; speedup vs baseline: 1.2355x; 1.1170x over previous
//
#include <hip/hip_runtime.h>
#include <hip/hip_bf16.h>

constexpr int Bb = 8, Ls = 2048, Dd = 512, Rr = 512;
constexpr int M1 = Bb * Ls;  // 16384

typedef _Float16 h8v __attribute__((ext_vector_type(8)));  // 8 fp16 (4 VGPRs)
typedef _Float16 h4v __attribute__((ext_vector_type(4)));  // 4 fp16 (8 B)
typedef float f4v __attribute__((ext_vector_type(4)));     // 4 fp32

__device__ __forceinline__ void async_copy16(const void* g, void* l) {
  __builtin_amdgcn_global_load_lds((const __attribute__((address_space(1))) unsigned int*)g,
                                   (__attribute__((address_space(3))) unsigned int*)l, 16, 0, 0);
}

// XCD-aware swizzle: blocks sharing an A-strip (same y) land 8 apart in the
// flattened hw id -> same XCD's L2. Bijective; requires gy*gz % 8 == 0.
__device__ __forceinline__ void swizzle_xy(int& x, int& yy) {
  const int NX = gridDim.x;
  const int lin = ((int)blockIdx.z * (int)gridDim.y + (int)blockIdx.y) * NX + (int)blockIdx.x;
  const int xcd = lin & 7;
  const int w = lin >> 3;
  x = w % NX;
  yy = (w / NX) * 8 + xcd;
}

// ---------------------------------------------------------------------------
// prep_all: one launch for
//   blocks [0, 2048): query fp32 -> qs fp16 (B,L,D) + qt fp16 (B,D,L) (64x64 tiles)
//   blocks [2048, 2304): Wq -> fp16
//   blocks [2304, 3328): Wc -> fp16
//   blocks [3328, 3456): iw = 1/w^2, c2 = -2c/w^2 (fp16), cc[r] = sum c^2/w^2
// ---------------------------------------------------------------------------
__global__ __launch_bounds__(256) void prep_all(
    const float* __restrict__ q, _Float16* __restrict__ qs, _Float16* __restrict__ qt,
    const float* __restrict__ Wq, _Float16* __restrict__ wq,
    const float* __restrict__ Wc, _Float16* __restrict__ wc,
    const float* __restrict__ centers, const float* __restrict__ widths,
    _Float16* __restrict__ iwh, _Float16* __restrict__ c2h, float* __restrict__ cc) {
  const int bid = blockIdx.x, tid = threadIdx.x;
  if (bid < 2048) {
    __shared__ float t[64][65];
    const int b = bid >> 8;              // 8 batches
    const int l0 = ((bid >> 3) & 31) * 64;  // 32 l-tiles
    const int d0 = (bid & 7) * 64;          // 8 d-tiles
    const int r = tid >> 4, c4 = (tid & 15) * 4;
#pragma unroll
    for (int i = 0; i < 4; ++i) {
      const int l = r + i * 16;
      const float4 v = *(const float4*)&q[((long)b * Ls + l0 + l) * Dd + d0 + c4];
      t[l][c4] = v.x; t[l][c4 + 1] = v.y; t[l][c4 + 2] = v.z; t[l][c4 + 3] = v.w;
      h4v h = {(_Float16)v.x, (_Float16)v.y, (_Float16)v.z, (_Float16)v.w};
      *(h4v*)&qs[((long)b * Ls + l0 + l) * Dd + d0 + c4] = h;
    }
    __syncthreads();
#pragma unroll
    for (int i = 0; i < 4; ++i) {
      const int d = r + i * 16;
      h4v h = {(_Float16)t[c4][d], (_Float16)t[c4 + 1][d],
               (_Float16)t[c4 + 2][d], (_Float16)t[c4 + 3][d]};
      *(h4v*)&qt[((long)b * Dd + d0 + d) * Ls + l0 + c4] = h;
    }
  } else if (bid < 2304) {
    const int i = (bid - 2048) * 256 + tid;
    float4 v = *(const float4*)&Wq[(long)i * 4];
    h4v o = {(_Float16)v.x, (_Float16)v.y, (_Float16)v.z, (_Float16)v.w};
    *(h4v*)&wq[(long)i * 4] = o;
  } else if (bid < 3328) {
    const int i = (bid - 2304) * 256 + tid;
    float4 v = *(const float4*)&Wc[(long)i * 4];
    h4v o = {(_Float16)v.x, (_Float16)v.y, (_Float16)v.z, (_Float16)v.w};
    *(h4v*)&wc[(long)i * 4] = o;
  } else {
    const int wave = tid >> 6, lane = tid & 63;
    const int r = (bid - 3328) * 4 + wave;
    float s = 0.f;
#pragma unroll
    for (int j = 0; j < 8; ++j) {
      const int d = j * 64 + lane;
      const float c = centers[(long)r * Dd + d];
      const float w = widths[(long)r * Dd + d];
      const float iw = 1.0f / (w * w);
      iwh[(long)r * Dd + d] = (_Float16)iw;
      c2h[(long)r * Dd + d] = (_Float16)(-2.0f * c * iw);
      s += c * c * iw;
    }
#pragma unroll
    for (int o = 32; o > 0; o >>= 1) s += __shfl_xor(s, o, 64);
    if (lane == 0) cc[r] = s;
  }
}

// cq16[i] = fp16(p0[i] + p1[i] + bc[i % 512])   (split-K reduction + bias)
__global__ __launch_bounds__(256) void reduce_cq(const float* __restrict__ p0,
                                                 const float* __restrict__ p1,
                                                 const float* __restrict__ bc,
                                                 _Float16* __restrict__ d, int n4) {
  int i = blockIdx.x * 256 + threadIdx.x;
  if (i < n4) {
    float4 a = *(const float4*)&p0[(long)i * 4];
    float4 b = *(const float4*)&p1[(long)i * 4];
    int c = (i * 4) & 511;
    h4v o = {(_Float16)(a.x + b.x + bc[c]), (_Float16)(a.y + b.y + bc[c + 1]),
             (_Float16)(a.z + b.z + bc[c + 2]), (_Float16)(a.w + b.w + bc[c + 3])};
    *(h4v*)&d[(long)i * 4] = o;
  }
}

// ---------------------------------------------------------------------------
// fp16 MFMA GEMM: C = A * B^T. A: M x K (row stride ldA), B: N x K (ldB).
// Block tile (AI*32) x 128, BK=32, 256 threads = 4 waves (2x2). Swizzled.
// z-dim = batch (sA/sB/sC) and/or split-K slice (kstep: K offset = zz*kstep,
// output slice offset = zz*sC).
// EPI: 2 = fp16 out with bias (Ch = fp16(acc + bias[n]))
//      3 = fp32 out           (Cf = acc)
// ---------------------------------------------------------------------------
template <int AI, int EPI>
__global__ __launch_bounds__(256) void gemm_h(
    const _Float16* __restrict__ A, const _Float16* __restrict__ Bm,
    const float* __restrict__ bias, float* __restrict__ Cf,
    _Float16* __restrict__ Ch, int Kext, int ldA, int ldB, int ldC, int kstep,
    long sA, long sB, long sC) {
  constexpr int TM = AI * 32;
  __shared__ _Float16 As[TM * 32];
  __shared__ _Float16 Bs[128 * 32];
  int x, yy;
  swizzle_xy(x, yy);
  const int y = yy % (int)gridDim.y;
  const int zz = yy / (int)gridDim.y;
  const int n0 = x * 128;
  const int m0 = y * TM;
  const int kb = zz * kstep;
  const _Float16* Ab = A + (long)zz * sA;
  const _Float16* Bb = Bm + (long)zz * sB;

  const int tid = threadIdx.x;
  const int wave = tid >> 6, lane = tid & 63;
  const int wm = wave >> 1, wn = wave & 1;
  const int quad = lane >> 4, tr = lane & 15;
  const int lrow = lane >> 2;
  const int lcol = (lane & 3) * 8;

  f4v acc[AI][4];
#pragma unroll
  for (int i = 0; i < AI; ++i)
#pragma unroll
    for (int j = 0; j < 4; ++j) acc[i][j] = (f4v){0.f, 0.f, 0.f, 0.f};

  for (int k0 = 0; k0 < Kext; k0 += 32) {
    __syncthreads();
#pragma unroll
    for (int c = wave; c < TM / 16; c += 4) {
      const long g = (long)(m0 + c * 16 + lrow) * ldA + kb + k0 + lcol;
      async_copy16(Ab + g, As + c * 512);
    }
#pragma unroll
    for (int c = wave; c < 8; c += 4) {
      const long g = (long)(n0 + c * 16 + lrow) * ldB + kb + k0 + lcol;
      async_copy16(Bb + g, Bs + c * 512);
    }
    __syncthreads();

    h8v af[AI], bf[4];
#pragma unroll
    for (int i = 0; i < AI; ++i)
      af[i] = *(const h8v*)&As[(wm * (AI * 16) + i * 16 + tr) * 32 + quad * 8];
#pragma unroll
    for (int j = 0; j < 4; ++j)
      bf[j] = *(const h8v*)&Bs[(wn * 64 + j * 16 + tr) * 32 + quad * 8];
#pragma unroll
    for (int i = 0; i < AI; ++i)
#pragma unroll
      for (int j = 0; j < 4; ++j)
        acc[i][j] = __builtin_amdgcn_mfma_f32_16x16x32_f16(af[i], bf[j], acc[i][j], 0, 0, 0);
  }

  float* Cfb = Cf ? Cf + (long)zz * sC : nullptr;
  _Float16* Chb = Ch ? Ch + (long)zz * sC : nullptr;
#pragma unroll
  for (int i = 0; i < AI; ++i)
#pragma unroll
    for (int j = 0; j < 4; ++j) {
      const int rbase = m0 + wm * (AI * 16) + i * 16 + quad * 4;
      const int cg = n0 + wn * 64 + j * 16 + tr;
#pragma unroll
      for (int r = 0; r < 4; ++r) {
        const float v = acc[i][j][r];
        const long row = rbase + r;
        if (EPI == 2) {
          Chb[row * (long)ldC + cg] = (_Float16)(v + bias[cg]);
        } else if (EPI == 3) {
          Cfb[row * (long)ldC + cg] = v;
        }
      }
    }
}

// ---------------------------------------------------------------------------
// zq_gemm: z[m,n] = -(1/1024)*( sum_k q^2[m,k]*iw[n,k] + q[m,k]*c2[n,k] + cc[n] )
// A-fragments squared IN REGISTERS (v_pk_mul_f16). 128x128, 24 KB LDS.
// ---------------------------------------------------------------------------
__global__ __launch_bounds__(256) void zq_gemm(
    const _Float16* __restrict__ Q, const _Float16* __restrict__ Iw,
    const _Float16* __restrict__ C2, const float* __restrict__ cc,
    float* __restrict__ Z) {
  __shared__ _Float16 As[128 * 32];
  __shared__ _Float16 B1[128 * 32];
  __shared__ _Float16 B2[128 * 32];
  int x, yy;
  swizzle_xy(x, yy);
  const int n0 = x * 128;
  const int m0 = yy * 128;

  const int tid = threadIdx.x;
  const int wave = tid >> 6, lane = tid & 63;
  const int wm = wave >> 1, wn = wave & 1;
  const int quad = lane >> 4, tr = lane & 15;
  const int lrow = lane >> 2;
  const int lcol = (lane & 3) * 8;

  f4v acc[4][4];
#pragma unroll
  for (int i = 0; i < 4; ++i)
#pragma unroll
    for (int j = 0; j < 4; ++j) acc[i][j] = (f4v){0.f, 0.f, 0.f, 0.f};

  for (int k0 = 0; k0 < 512; k0 += 32) {
    __syncthreads();
#pragma unroll
    for (int c = wave; c < 8; c += 4) {
      const long ga = (long)(m0 + c * 16 + lrow) * 512 + k0 + lcol;
      async_copy16(Q + ga, As + c * 512);
      const long gb = (long)(n0 + c * 16 + lrow) * 512 + k0 + lcol;
      async_copy16(Iw + gb, B1 + c * 512);
      async_copy16(C2 + gb, B2 + c * 512);
    }
    __syncthreads();

    h8v af[4], af2[4], b1[4], b2[4];
#pragma unroll
    for (int i = 0; i < 4; ++i) {
      af[i] = *(const h8v*)&As[(wm * 64 + i * 16 + tr) * 32 + quad * 8];
      af2[i] = af[i] * af[i];
    }
#pragma unroll
    for (int j = 0; j < 4; ++j) {
      b1[j] = *(const h8v*)&B1[(wn * 64 + j * 16 + tr) * 32 + quad * 8];
      b2[j] = *(const h8v*)&B2[(wn * 64 + j * 16 + tr) * 32 + quad * 8];
    }
#pragma unroll
    for (int i = 0; i < 4; ++i)
#pragma unroll
      for (int j = 0; j < 4; ++j) {
        acc[i][j] = __builtin_amdgcn_mfma_f32_16x16x32_f16(af2[i], b1[j], acc[i][j], 0, 0, 0);
        acc[i][j] = __builtin_amdgcn_mfma_f32_16x16x32_f16(af[i], b2[j], acc[i][j], 0, 0, 0);
      }
  }

  constexpr float zs = -0.0009765625f;  // -(0.5/512)
#pragma unroll
  for (int i = 0; i < 4; ++i)
#pragma unroll
    for (int j = 0; j < 4; ++j) {
      const int rbase = m0 + wm * 64 + i * 16 + quad * 4;
      const int cg = n0 + wn * 64 + j * 16 + tr;
      const float ccv = cc[cg];
#pragma unroll
      for (int r = 0; r < 4; ++r)
        Z[(long)(rbase + r) * 512 + cg] = (acc[i][j][r] + ccv) * zs;
    }
}

// ---------------------------------------------------------------------------
// softmax over R=512: read z fp32, write Fss fp16. One wave per row.
// ---------------------------------------------------------------------------
__global__ __launch_bounds__(256) void softmax_h(const float* __restrict__ Z,
                                                 _Float16* __restrict__ F) {
  const int wave = threadIdx.x >> 6;
  const int lane = threadIdx.x & 63;
  const long row = (long)blockIdx.x * 4 + wave;
  const float* p = Z + row * Rr;
  float4 v0 = *(const float4*)&p[lane * 8];
  float4 v1 = *(const float4*)&p[lane * 8 + 4];
  float v[8] = {v0.x, v0.y, v0.z, v0.w, v1.x, v1.y, v1.z, v1.w};
  float m = v[0];
#pragma unroll
  for (int i = 1; i < 8; ++i) m = fmaxf(m, v[i]);
#pragma unroll
  for (int s = 32; s > 0; s >>= 1) m = fmaxf(m, __shfl_xor(m, s, 64));
  float sum = 0.f;
#pragma unroll
  for (int i = 0; i < 8; ++i) {
    v[i] = __expf(v[i] - m);
    sum += v[i];
  }
#pragma unroll
  for (int s = 32; s > 0; s >>= 1) sum += __shfl_xor(sum, s, 64);
  const float inv = 1.0f / sum;
  h8v o;
#pragma unroll
  for (int i = 0; i < 8; ++i) o[i] = (_Float16)(v[i] * inv);
  *(h8v*)&F[row * Rr + lane * 8] = o;
}

// ---------------------------------------------------------------------------
extern "C" void kernel_launch(void* const* d_in, const int* in_sizes, int n_in,
                              void* d_out, int out_size, void* d_ws, size_t ws_size,
                              hipStream_t stream) {
  const float* query   = (const float*)d_in[0];
  const float* Wq      = (const float*)d_in[1];
  const float* bq      = (const float*)d_in[2];
  const float* Wc      = (const float*)d_in[3];
  const float* bc      = (const float*)d_in[4];
  const float* centers = (const float*)d_in[5];
  const float* widths  = (const float*)d_in[6];
  float* out = (float*)d_out;

  char* base = (char*)d_ws;
  auto alloc = [&](size_t bytes) {
    char* p = base;
    base += (bytes + 255) & ~(size_t)255;
    return p;
  };
  _Float16* qs  = (_Float16*)alloc((size_t)M1 * Dd * 2);      // 16.8 MB
  _Float16* qt  = (_Float16*)alloc((size_t)M1 * Dd * 2);      // 16.8 MB (B,D,L)
  _Float16* q16 = (_Float16*)alloc((size_t)M1 * Dd * 2);      // 16.8 MB
  float*    z   = (float*)alloc((size_t)M1 * Rr * 4);         // 33.6 MB; reused as conq partials
  _Float16* fs  = (_Float16*)alloc((size_t)M1 * Rr * 2);      // 16.8 MB
  _Float16* wq  = (_Float16*)alloc((size_t)Dd * Dd * 2);
  _Float16* wc  = (_Float16*)alloc((size_t)Rr * Ls * 2);
  _Float16* iwh = (_Float16*)alloc((size_t)Rr * Dd * 2);
  _Float16* c2h = (_Float16*)alloc((size_t)Rr * Dd * 2);
  float*    cc  = (float*)alloc((size_t)Rr * 4);
  _Float16* cq  = (_Float16*)alloc((size_t)Bb * Dd * Rr * 2); // 4.2 MB

  // conq split-K partial buffers reuse z (dead after softmax): 2 x 8.4 MB
  float* cqp = z;

  // all conversions + fuzzy-param precompute, one launch
  prep_all<<<3456, 256, 0, stream>>>(query, qs, qt, Wq, wq, Wc, wc,
                                     centers, widths, iwh, c2h, cc);

  // q-GEMM: q16 = fp16(query @ Wq^T + bq)
  gemm_h<4, 2><<<dim3(Dd / 128, M1 / 128, 1), 256, 0, stream>>>(
      qs, wq, bq, nullptr, q16, Dd, Dd, Dd, Dd, 0, 0, 0, 0);

  // z-GEMM with in-register squared A-fragments
  zq_gemm<<<dim3(Rr / 128, M1 / 128, 1), 256, 0, stream>>>(q16, iwh, c2h, cc, z);

  // softmax -> Fss fp16
  softmax_h<<<M1 / 4, 256, 0, stream>>>(z, fs);

  // conq split-K=2, plain stores to private partial slices (no atomics):
  // cqp[s][(b,d), r] = qt[(b,d), s*1024 : (s+1)*1024] . Wc[r, same]
  gemm_h<2, 3><<<dim3(Rr / 128, (Bb * Dd) / 64, 2), 256, 0, stream>>>(
      qt, wc, nullptr, cqp, nullptr, 1024, Ls, Ls, Rr, 1024,
      0, 0, (long)Bb * Dd * Rr);
  reduce_cq<<<(Bb * Dd * Rr / 4 + 255) / 256, 256, 0, stream>>>(
      cqp, cqp + (long)Bb * Dd * Rr, bc, cq, Bb * Dd * Rr / 4);

  // out-GEMM: out[b] = Fss[b] @ cq[b]^T
  gemm_h<4, 3><<<dim3(Dd / 128, Ls / 128, Bb), 256, 0, stream>>>(
      fs, cq, nullptr, out, nullptr, Rr, Rr, Rr, Dd, 0,
      (long)Ls * Rr, (long)Dd * Rr, (long)Ls * Dd);
}

// Round 7
// 187.586 us; speedup vs baseline: 1.2519x; 1.0133x over previous
//
#include <hip/hip_runtime.h>
#include <hip/hip_bf16.h>

constexpr int Bb = 8, Ls = 2048, Dd = 512, Rr = 512;
constexpr int M1 = Bb * Ls;  // 16384

typedef _Float16 h8v __attribute__((ext_vector_type(8)));  // 8 fp16 (4 VGPRs)
typedef _Float16 h4v __attribute__((ext_vector_type(4)));  // 4 fp16 (8 B)
typedef float f4v __attribute__((ext_vector_type(4)));     // 4 fp32

__device__ __forceinline__ void async_copy16(const void* g, void* l) {
  __builtin_amdgcn_global_load_lds((const __attribute__((address_space(1))) unsigned int*)g,
                                   (__attribute__((address_space(3))) unsigned int*)l, 16, 0, 0);
}

// XCD-aware swizzle: blocks sharing an A-strip (same y) land 8 apart in the
// flattened hw id -> same XCD's L2. Bijective; requires gy*gz % 8 == 0.
__device__ __forceinline__ void swizzle_xy(int& x, int& yy) {
  const int NX = gridDim.x;
  const int lin = ((int)blockIdx.z * (int)gridDim.y + (int)blockIdx.y) * NX + (int)blockIdx.x;
  const int xcd = lin & 7;
  const int w = lin >> 3;
  x = w % NX;
  yy = (w / NX) * 8 + xcd;
}

// ---------------------------------------------------------------------------
// prep_all: one launch for
//   blocks [0, 2048): query fp32 -> qs fp16 (B,L,D) + qt fp16 (B,D,L)
//   blocks [2048, 2304): Wq -> fp16
//   blocks [2304, 3328): Wc -> fp16
//   blocks [3328, 3456): iw = 1/w^2, c2 = -2c/w^2 (fp16), cc[r] = sum c^2/w^2
// ---------------------------------------------------------------------------
__global__ __launch_bounds__(256) void prep_all(
    const float* __restrict__ q, _Float16* __restrict__ qs, _Float16* __restrict__ qt,
    const float* __restrict__ Wq, _Float16* __restrict__ wq,
    const float* __restrict__ Wc, _Float16* __restrict__ wc,
    const float* __restrict__ centers, const float* __restrict__ widths,
    _Float16* __restrict__ iwh, _Float16* __restrict__ c2h, float* __restrict__ cc) {
  const int bid = blockIdx.x, tid = threadIdx.x;
  if (bid < 2048) {
    __shared__ float t[64][65];
    const int b = bid >> 8;
    const int l0 = ((bid >> 3) & 31) * 64;
    const int d0 = (bid & 7) * 64;
    const int r = tid >> 4, c4 = (tid & 15) * 4;
#pragma unroll
    for (int i = 0; i < 4; ++i) {
      const int l = r + i * 16;
      const float4 v = *(const float4*)&q[((long)b * Ls + l0 + l) * Dd + d0 + c4];
      t[l][c4] = v.x; t[l][c4 + 1] = v.y; t[l][c4 + 2] = v.z; t[l][c4 + 3] = v.w;
      h4v h = {(_Float16)v.x, (_Float16)v.y, (_Float16)v.z, (_Float16)v.w};
      *(h4v*)&qs[((long)b * Ls + l0 + l) * Dd + d0 + c4] = h;
    }
    __syncthreads();
#pragma unroll
    for (int i = 0; i < 4; ++i) {
      const int d = r + i * 16;
      h4v h = {(_Float16)t[c4][d], (_Float16)t[c4 + 1][d],
               (_Float16)t[c4 + 2][d], (_Float16)t[c4 + 3][d]};
      *(h4v*)&qt[((long)b * Dd + d0 + d) * Ls + l0 + c4] = h;
    }
  } else if (bid < 2304) {
    const int i = (bid - 2048) * 256 + tid;
    float4 v = *(const float4*)&Wq[(long)i * 4];
    h4v o = {(_Float16)v.x, (_Float16)v.y, (_Float16)v.z, (_Float16)v.w};
    *(h4v*)&wq[(long)i * 4] = o;
  } else if (bid < 3328) {
    const int i = (bid - 2304) * 256 + tid;
    float4 v = *(const float4*)&Wc[(long)i * 4];
    h4v o = {(_Float16)v.x, (_Float16)v.y, (_Float16)v.z, (_Float16)v.w};
    *(h4v*)&wc[(long)i * 4] = o;
  } else {
    const int wave = tid >> 6, lane = tid & 63;
    const int r = (bid - 3328) * 4 + wave;
    float s = 0.f;
#pragma unroll
    for (int j = 0; j < 8; ++j) {
      const int d = j * 64 + lane;
      const float c = centers[(long)r * Dd + d];
      const float w = widths[(long)r * Dd + d];
      const float iw = 1.0f / (w * w);
      iwh[(long)r * Dd + d] = (_Float16)iw;
      c2h[(long)r * Dd + d] = (_Float16)(-2.0f * c * iw);
      s += c * c * iw;
    }
#pragma unroll
    for (int o = 32; o > 0; o >>= 1) s += __shfl_xor(s, o, 64);
    if (lane == 0) cc[r] = s;
  }
}

// cq16[i] = fp16(p0[i] + p1[i] + bc[i % 512])   (split-K reduction + bias)
__global__ __launch_bounds__(256) void reduce_cq(const float* __restrict__ p0,
                                                 const float* __restrict__ p1,
                                                 const float* __restrict__ bc,
                                                 _Float16* __restrict__ d, int n4) {
  int i = blockIdx.x * 256 + threadIdx.x;
  if (i < n4) {
    float4 a = *(const float4*)&p0[(long)i * 4];
    float4 b = *(const float4*)&p1[(long)i * 4];
    int c = (i * 4) & 511;
    h4v o = {(_Float16)(a.x + b.x + bc[c]), (_Float16)(a.y + b.y + bc[c + 1]),
             (_Float16)(a.z + b.z + bc[c + 2]), (_Float16)(a.w + b.w + bc[c + 3])};
    *(h4v*)&d[(long)i * 4] = o;
  }
}

// ---------------------------------------------------------------------------
// fp16 MFMA GEMM, 512 threads = 8 waves (2 wm x 4 wn). Block tile
// (WM*32) x 128; each wave (WM*16) x 32 = WM x 2 mfma 16x16x32 tiles.
// acc[WM][2], af[WM], bf[2]. __launch_bounds__(512,4) caps VGPR at 128 so
// 2 blocks/CU = 16 waves/CU co-reside.
// EPI: 2 = fp16 out + bias (Ch), 3 = fp32 out (Cf)
// ---------------------------------------------------------------------------
template <int WM, int EPI>
__global__ __launch_bounds__(512, 4) void gemm_h(
    const _Float16* __restrict__ A, const _Float16* __restrict__ Bm,
    const float* __restrict__ bias, float* __restrict__ Cf,
    _Float16* __restrict__ Ch, int Kext, int ldA, int ldB, int ldC, int kstep,
    long sA, long sB, long sC) {
  constexpr int TM = WM * 32;
  __shared__ _Float16 As[TM * 32];
  __shared__ _Float16 Bs[128 * 32];
  int x, yy;
  swizzle_xy(x, yy);
  const int y = yy % (int)gridDim.y;
  const int zz = yy / (int)gridDim.y;
  const int n0 = x * 128;
  const int m0 = y * TM;
  const int kb = zz * kstep;
  const _Float16* Ab = A + (long)zz * sA;
  const _Float16* Bb = Bm + (long)zz * sB;

  const int tid = threadIdx.x;
  const int wave = tid >> 6, lane = tid & 63;
  const int wm = wave >> 2, wn = wave & 3;
  const int quad = lane >> 4, tr = lane & 15;
  const int lrow = lane >> 2;
  const int lcol = (lane & 3) * 8;

  f4v acc[WM][2];
#pragma unroll
  for (int i = 0; i < WM; ++i)
#pragma unroll
    for (int j = 0; j < 2; ++j) acc[i][j] = (f4v){0.f, 0.f, 0.f, 0.f};

  for (int k0 = 0; k0 < Kext; k0 += 32) {
    __syncthreads();
#pragma unroll
    for (int c = wave; c < TM / 16; c += 8) {
      const long g = (long)(m0 + c * 16 + lrow) * ldA + kb + k0 + lcol;
      async_copy16(Ab + g, As + c * 512);
    }
#pragma unroll
    for (int c = wave; c < 8; c += 8) {
      const long g = (long)(n0 + c * 16 + lrow) * ldB + kb + k0 + lcol;
      async_copy16(Bb + g, Bs + c * 512);
    }
    __syncthreads();

    h8v af[WM], bf[2];
#pragma unroll
    for (int i = 0; i < WM; ++i)
      af[i] = *(const h8v*)&As[(wm * (WM * 16) + i * 16 + tr) * 32 + quad * 8];
#pragma unroll
    for (int j = 0; j < 2; ++j)
      bf[j] = *(const h8v*)&Bs[(wn * 32 + j * 16 + tr) * 32 + quad * 8];
#pragma unroll
    for (int i = 0; i < WM; ++i)
#pragma unroll
      for (int j = 0; j < 2; ++j)
        acc[i][j] = __builtin_amdgcn_mfma_f32_16x16x32_f16(af[i], bf[j], acc[i][j], 0, 0, 0);
  }

  float* Cfb = Cf ? Cf + (long)zz * sC : nullptr;
  _Float16* Chb = Ch ? Ch + (long)zz * sC : nullptr;
#pragma unroll
  for (int i = 0; i < WM; ++i)
#pragma unroll
    for (int j = 0; j < 2; ++j) {
      const int rbase = m0 + wm * (WM * 16) + i * 16 + quad * 4;
      const int cg = n0 + wn * 32 + j * 16 + tr;
#pragma unroll
      for (int r = 0; r < 4; ++r) {
        const float v = acc[i][j][r];
        const long row = rbase + r;
        if (EPI == 2) {
          Chb[row * (long)ldC + cg] = (_Float16)(v + bias[cg]);
        } else if (EPI == 3) {
          Cfb[row * (long)ldC + cg] = v;
        }
      }
    }
}

// ---------------------------------------------------------------------------
// zq_gemm (512 threads, 8 waves 2x4): z fp16 output.
// z[m,n] = -(1/1024)*( sum_k q^2[m,k]*iw[n,k] + q[m,k]*c2[n,k] + cc[n] )
// A-fragments squared in registers (v_pk_mul_f16). 128x128 tile, 24 KB LDS.
// ---------------------------------------------------------------------------
__global__ __launch_bounds__(512, 4) void zq_gemm(
    const _Float16* __restrict__ Q, const _Float16* __restrict__ Iw,
    const _Float16* __restrict__ C2, const float* __restrict__ cc,
    _Float16* __restrict__ Zh) {
  __shared__ _Float16 As[128 * 32];
  __shared__ _Float16 B1[128 * 32];
  __shared__ _Float16 B2[128 * 32];
  int x, yy;
  swizzle_xy(x, yy);
  const int n0 = x * 128;
  const int m0 = yy * 128;

  const int tid = threadIdx.x;
  const int wave = tid >> 6, lane = tid & 63;
  const int wm = wave >> 2, wn = wave & 3;
  const int quad = lane >> 4, tr = lane & 15;
  const int lrow = lane >> 2;
  const int lcol = (lane & 3) * 8;

  f4v acc[4][2];
#pragma unroll
  for (int i = 0; i < 4; ++i)
#pragma unroll
    for (int j = 0; j < 2; ++j) acc[i][j] = (f4v){0.f, 0.f, 0.f, 0.f};

  for (int k0 = 0; k0 < 512; k0 += 32) {
    __syncthreads();
    {  // 24 staging chunks over 8 waves: one A, one B1, one B2 each
      const long ga = (long)(m0 + wave * 16 + lrow) * 512 + k0 + lcol;
      async_copy16(Q + ga, As + wave * 512);
      const long gb = (long)(n0 + wave * 16 + lrow) * 512 + k0 + lcol;
      async_copy16(Iw + gb, B1 + wave * 512);
      async_copy16(C2 + gb, B2 + wave * 512);
    }
    __syncthreads();

    h8v af[4], af2[4], b1[2], b2[2];
#pragma unroll
    for (int i = 0; i < 4; ++i) {
      af[i] = *(const h8v*)&As[(wm * 64 + i * 16 + tr) * 32 + quad * 8];
      af2[i] = af[i] * af[i];
    }
#pragma unroll
    for (int j = 0; j < 2; ++j) {
      b1[j] = *(const h8v*)&B1[(wn * 32 + j * 16 + tr) * 32 + quad * 8];
      b2[j] = *(const h8v*)&B2[(wn * 32 + j * 16 + tr) * 32 + quad * 8];
    }
#pragma unroll
    for (int i = 0; i < 4; ++i)
#pragma unroll
      for (int j = 0; j < 2; ++j) {
        acc[i][j] = __builtin_amdgcn_mfma_f32_16x16x32_f16(af2[i], b1[j], acc[i][j], 0, 0, 0);
        acc[i][j] = __builtin_amdgcn_mfma_f32_16x16x32_f16(af[i], b2[j], acc[i][j], 0, 0, 0);
      }
  }

  constexpr float zs = -0.0009765625f;  // -(0.5/512)
#pragma unroll
  for (int i = 0; i < 4; ++i)
#pragma unroll
    for (int j = 0; j < 2; ++j) {
      const int rbase = m0 + wm * 64 + i * 16 + quad * 4;
      const int cg = n0 + wn * 32 + j * 16 + tr;
      const float ccv = cc[cg];
#pragma unroll
      for (int r = 0; r < 4; ++r)
        Zh[(long)(rbase + r) * 512 + cg] = (_Float16)((acc[i][j][r] + ccv) * zs);
    }
}

// ---------------------------------------------------------------------------
// softmax over R=512: read z fp16, write Fss fp16. One wave per row.
// ---------------------------------------------------------------------------
__global__ __launch_bounds__(256) void softmax_h(const _Float16* __restrict__ Zh,
                                                 _Float16* __restrict__ F) {
  const int wave = threadIdx.x >> 6;
  const int lane = threadIdx.x & 63;
  const long row = (long)blockIdx.x * 4 + wave;
  h8v zv = *(const h8v*)&Zh[row * Rr + lane * 8];
  float v[8];
#pragma unroll
  for (int i = 0; i < 8; ++i) v[i] = (float)zv[i];
  float m = v[0];
#pragma unroll
  for (int i = 1; i < 8; ++i) m = fmaxf(m, v[i]);
#pragma unroll
  for (int s = 32; s > 0; s >>= 1) m = fmaxf(m, __shfl_xor(m, s, 64));
  float sum = 0.f;
#pragma unroll
  for (int i = 0; i < 8; ++i) {
    v[i] = __expf(v[i] - m);
    sum += v[i];
  }
#pragma unroll
  for (int s = 32; s > 0; s >>= 1) sum += __shfl_xor(sum, s, 64);
  const float inv = 1.0f / sum;
  h8v o;
#pragma unroll
  for (int i = 0; i < 8; ++i) o[i] = (_Float16)(v[i] * inv);
  *(h8v*)&F[row * Rr + lane * 8] = o;
}

// ---------------------------------------------------------------------------
extern "C" void kernel_launch(void* const* d_in, const int* in_sizes, int n_in,
                              void* d_out, int out_size, void* d_ws, size_t ws_size,
                              hipStream_t stream) {
  const float* query   = (const float*)d_in[0];
  const float* Wq      = (const float*)d_in[1];
  const float* bq      = (const float*)d_in[2];
  const float* Wc      = (const float*)d_in[3];
  const float* bc      = (const float*)d_in[4];
  const float* centers = (const float*)d_in[5];
  const float* widths  = (const float*)d_in[6];
  float* out = (float*)d_out;

  char* base = (char*)d_ws;
  auto alloc = [&](size_t bytes) {
    char* p = base;
    base += (bytes + 255) & ~(size_t)255;
    return p;
  };
  _Float16* qs  = (_Float16*)alloc((size_t)M1 * Dd * 2);      // 16.8 MB
  _Float16* qt  = (_Float16*)alloc((size_t)M1 * Dd * 2);      // 16.8 MB (B,D,L)
  _Float16* q16 = (_Float16*)alloc((size_t)M1 * Dd * 2);      // 16.8 MB
  _Float16* zh  = (_Float16*)alloc((size_t)M1 * Rr * 2);      // 16.8 MB (z fp16)
  _Float16* fs  = (_Float16*)alloc((size_t)M1 * Rr * 2);      // 16.8 MB
  _Float16* wq  = (_Float16*)alloc((size_t)Dd * Dd * 2);
  _Float16* wc  = (_Float16*)alloc((size_t)Rr * Ls * 2);
  _Float16* iwh = (_Float16*)alloc((size_t)Rr * Dd * 2);
  _Float16* c2h = (_Float16*)alloc((size_t)Rr * Dd * 2);
  float*    cc  = (float*)alloc((size_t)Rr * 4);
  float*    cqp = (float*)alloc((size_t)2 * Bb * Dd * Rr * 4); // 16.8 MB partials
  _Float16* cq  = (_Float16*)alloc((size_t)Bb * Dd * Rr * 2);  // 4.2 MB

  // all conversions + fuzzy-param precompute, one launch
  prep_all<<<3456, 256, 0, stream>>>(query, qs, qt, Wq, wq, Wc, wc,
                                     centers, widths, iwh, c2h, cc);

  // q-GEMM: q16 = fp16(query @ Wq^T + bq)   grid (4,128) = 512 blocks
  gemm_h<4, 2><<<dim3(Dd / 128, M1 / 128, 1), 512, 0, stream>>>(
      qs, wq, bq, nullptr, q16, Dd, Dd, Dd, Dd, 0, 0, 0, 0);

  // z-GEMM (in-register squared A), fp16 z out   grid (4,128)
  zq_gemm<<<dim3(Rr / 128, M1 / 128, 1), 512, 0, stream>>>(q16, iwh, c2h, cc, zh);

  // softmax -> Fss fp16
  softmax_h<<<M1 / 4, 256, 0, stream>>>(zh, fs);

  // conq split-K=2, plain stores to private partial slices:
  // cqp[s][(b,d), r] = qt[(b,d), s*1024:(s+1)*1024] . Wc[r, same]
  gemm_h<2, 3><<<dim3(Rr / 128, (Bb * Dd) / 64, 2), 512, 0, stream>>>(
      qt, wc, nullptr, cqp, nullptr, 1024, Ls, Ls, Rr, 1024,
      0, 0, (long)Bb * Dd * Rr);
  reduce_cq<<<(Bb * Dd * Rr / 4 + 255) / 256, 256, 0, stream>>>(
      cqp, cqp + (long)Bb * Dd * Rr, bc, cq, Bb * Dd * Rr / 4);

  // out-GEMM: out[b] = Fss[b] @ cq[b]^T   grid (4,16,8)
  gemm_h<4, 3><<<dim3(Dd / 128, Ls / 128, Bb), 512, 0, stream>>>(
      fs, cq, nullptr, out, nullptr, Rr, Rr, Rr, Dd, 0,
      (long)Ls * Rr, (long)Dd * Rr, (long)Ls * Dd);
}

// Round 8
// 172.693 us; speedup vs baseline: 1.3599x; 1.0862x over previous
//
#include <hip/hip_runtime.h>
#include <hip/hip_bf16.h>

constexpr int Bb = 8, Ls = 2048, Dd = 512, Rr = 512;
constexpr int M1 = Bb * Ls;  // 16384

typedef _Float16 h8v __attribute__((ext_vector_type(8)));  // 8 fp16 (4 VGPRs)
typedef _Float16 h4v __attribute__((ext_vector_type(4)));  // 4 fp16 (8 B)
typedef float f4v __attribute__((ext_vector_type(4)));     // 4 fp32

__device__ __forceinline__ void async_copy16(const void* g, void* l) {
  __builtin_amdgcn_global_load_lds((const __attribute__((address_space(1))) unsigned int*)g,
                                   (__attribute__((address_space(3))) unsigned int*)l, 16, 0, 0);
}

// XCD-aware swizzle: blocks sharing an A-strip (same y) land 8 apart in the
// flattened hw id -> same XCD's L2. Bijective; requires gy*gz % 8 == 0.
__device__ __forceinline__ void swizzle_xy(int& x, int& yy) {
  const int NX = gridDim.x;
  const int lin = ((int)blockIdx.z * (int)gridDim.y + (int)blockIdx.y) * NX + (int)blockIdx.x;
  const int xcd = lin & 7;
  const int w = lin >> 3;
  x = w % NX;
  yy = (w / NX) * 8 + xcd;
}

// ---------------------------------------------------------------------------
// prep_all: one launch for
//   blocks [0, 2048): query fp32 -> qs fp16 (B,L,D) + qt fp16 (B,D,L)
//   blocks [2048, 2304): Wq -> fp16
//   blocks [2304, 3328): Wc -> fp16
//   blocks [3328, 3456): iw = 1/w^2, c2 = -2c/w^2 (fp16), cc[r] = sum c^2/w^2
// ---------------------------------------------------------------------------
__global__ __launch_bounds__(256) void prep_all(
    const float* __restrict__ q, _Float16* __restrict__ qs, _Float16* __restrict__ qt,
    const float* __restrict__ Wq, _Float16* __restrict__ wq,
    const float* __restrict__ Wc, _Float16* __restrict__ wc,
    const float* __restrict__ centers, const float* __restrict__ widths,
    _Float16* __restrict__ iwh, _Float16* __restrict__ c2h, float* __restrict__ cc) {
  const int bid = blockIdx.x, tid = threadIdx.x;
  if (bid < 2048) {
    __shared__ float t[64][65];
    const int b = bid >> 8;
    const int l0 = ((bid >> 3) & 31) * 64;
    const int d0 = (bid & 7) * 64;
    const int r = tid >> 4, c4 = (tid & 15) * 4;
#pragma unroll
    for (int i = 0; i < 4; ++i) {
      const int l = r + i * 16;
      const float4 v = *(const float4*)&q[((long)b * Ls + l0 + l) * Dd + d0 + c4];
      t[l][c4] = v.x; t[l][c4 + 1] = v.y; t[l][c4 + 2] = v.z; t[l][c4 + 3] = v.w;
      h4v h = {(_Float16)v.x, (_Float16)v.y, (_Float16)v.z, (_Float16)v.w};
      *(h4v*)&qs[((long)b * Ls + l0 + l) * Dd + d0 + c4] = h;
    }
    __syncthreads();
#pragma unroll
    for (int i = 0; i < 4; ++i) {
      const int d = r + i * 16;
      h4v h = {(_Float16)t[c4][d], (_Float16)t[c4 + 1][d],
               (_Float16)t[c4 + 2][d], (_Float16)t[c4 + 3][d]};
      *(h4v*)&qt[((long)b * Dd + d0 + d) * Ls + l0 + c4] = h;
    }
  } else if (bid < 2304) {
    const int i = (bid - 2048) * 256 + tid;
    float4 v = *(const float4*)&Wq[(long)i * 4];
    h4v o = {(_Float16)v.x, (_Float16)v.y, (_Float16)v.z, (_Float16)v.w};
    *(h4v*)&wq[(long)i * 4] = o;
  } else if (bid < 3328) {
    const int i = (bid - 2304) * 256 + tid;
    float4 v = *(const float4*)&Wc[(long)i * 4];
    h4v o = {(_Float16)v.x, (_Float16)v.y, (_Float16)v.z, (_Float16)v.w};
    *(h4v*)&wc[(long)i * 4] = o;
  } else {
    const int wave = tid >> 6, lane = tid & 63;
    const int r = (bid - 3328) * 4 + wave;
    float s = 0.f;
#pragma unroll
    for (int j = 0; j < 8; ++j) {
      const int d = j * 64 + lane;
      const float c = centers[(long)r * Dd + d];
      const float w = widths[(long)r * Dd + d];
      const float iw = 1.0f / (w * w);
      iwh[(long)r * Dd + d] = (_Float16)iw;
      c2h[(long)r * Dd + d] = (_Float16)(-2.0f * c * iw);
      s += c * c * iw;
    }
#pragma unroll
    for (int o = 32; o > 0; o >>= 1) s += __shfl_xor(s, o, 64);
    if (lane == 0) cc[r] = s;
  }
}

// cq16[i] = fp16(p0[i] + p1[i] + bc[i % 512])   (split-K reduction + bias)
__global__ __launch_bounds__(256) void reduce_cq(const float* __restrict__ p0,
                                                 const float* __restrict__ p1,
                                                 const float* __restrict__ bc,
                                                 _Float16* __restrict__ d, int n4) {
  int i = blockIdx.x * 256 + threadIdx.x;
  if (i < n4) {
    float4 a = *(const float4*)&p0[(long)i * 4];
    float4 b = *(const float4*)&p1[(long)i * 4];
    int c = (i * 4) & 511;
    h4v o = {(_Float16)(a.x + b.x + bc[c]), (_Float16)(a.y + b.y + bc[c + 1]),
             (_Float16)(a.z + b.z + bc[c + 2]), (_Float16)(a.w + b.w + bc[c + 3])};
    *(h4v*)&d[(long)i * 4] = o;
  }
}

// ---------------------------------------------------------------------------
// fp16 MFMA GEMM, 512 threads = 8 waves (2 wm x 4 wn). Block tile
// (WM*32) x 128. BK=64 realized as a PING-PONG PAIR of BK=32 tiles:
// one barrier pair per 64 of K (half the barrier drains of BK=32) while each
// tile keeps the 32-fp16 row stride whose b128 fragment reads spread evenly
// over all 32 LDS banks (a single 64-wide tile would serialize on 16 banks;
// global_load_lds forbids padding).
// EPI: 2 = fp16 out + bias (Ch), 3 = fp32 out (Cf)
// ---------------------------------------------------------------------------
template <int WM, int EPI>
__global__ __launch_bounds__(512, 4) void gemm_h(
    const _Float16* __restrict__ A, const _Float16* __restrict__ Bm,
    const float* __restrict__ bias, float* __restrict__ Cf,
    _Float16* __restrict__ Ch, int Kext, int ldA, int ldB, int ldC, int kstep,
    long sA, long sB, long sC) {
  constexpr int TM = WM * 32;
  __shared__ _Float16 As[2][TM * 32];
  __shared__ _Float16 Bs[2][128 * 32];
  int x, yy;
  swizzle_xy(x, yy);
  const int y = yy % (int)gridDim.y;
  const int zz = yy / (int)gridDim.y;
  const int n0 = x * 128;
  const int m0 = y * TM;
  const int kb = zz * kstep;
  const _Float16* Ab = A + (long)zz * sA;
  const _Float16* Bb = Bm + (long)zz * sB;

  const int tid = threadIdx.x;
  const int wave = tid >> 6, lane = tid & 63;
  const int wm = wave >> 2, wn = wave & 3;
  const int quad = lane >> 4, tr = lane & 15;
  const int lrow = lane >> 2;
  const int lcol = (lane & 3) * 8;

  f4v acc[WM][2];
#pragma unroll
  for (int i = 0; i < WM; ++i)
#pragma unroll
    for (int j = 0; j < 2; ++j) acc[i][j] = (f4v){0.f, 0.f, 0.f, 0.f};

  for (int k0 = 0; k0 < Kext; k0 += 64) {
    __syncthreads();
#pragma unroll
    for (int c = wave; c < TM / 16; c += 8) {
      const long g = (long)(m0 + c * 16 + lrow) * ldA + kb + k0 + lcol;
      async_copy16(Ab + g, &As[0][c * 512]);
      async_copy16(Ab + g + 32, &As[1][c * 512]);
    }
#pragma unroll
    for (int c = wave; c < 8; c += 8) {
      const long g = (long)(n0 + c * 16 + lrow) * ldB + kb + k0 + lcol;
      async_copy16(Bb + g, &Bs[0][c * 512]);
      async_copy16(Bb + g + 32, &Bs[1][c * 512]);
    }
    __syncthreads();

#pragma unroll
    for (int h = 0; h < 2; ++h) {
      h8v af[WM], bf[2];
#pragma unroll
      for (int i = 0; i < WM; ++i)
        af[i] = *(const h8v*)&As[h][(wm * (WM * 16) + i * 16 + tr) * 32 + quad * 8];
#pragma unroll
      for (int j = 0; j < 2; ++j)
        bf[j] = *(const h8v*)&Bs[h][(wn * 32 + j * 16 + tr) * 32 + quad * 8];
#pragma unroll
      for (int i = 0; i < WM; ++i)
#pragma unroll
        for (int j = 0; j < 2; ++j)
          acc[i][j] = __builtin_amdgcn_mfma_f32_16x16x32_f16(af[i], bf[j], acc[i][j], 0, 0, 0);
    }
  }

  float* Cfb = Cf ? Cf + (long)zz * sC : nullptr;
  _Float16* Chb = Ch ? Ch + (long)zz * sC : nullptr;
#pragma unroll
  for (int i = 0; i < WM; ++i)
#pragma unroll
    for (int j = 0; j < 2; ++j) {
      const int rbase = m0 + wm * (WM * 16) + i * 16 + quad * 4;
      const int cg = n0 + wn * 32 + j * 16 + tr;
#pragma unroll
      for (int r = 0; r < 4; ++r) {
        const float v = acc[i][j][r];
        const long row = rbase + r;
        if (EPI == 2) {
          Chb[row * (long)ldC + cg] = (_Float16)(v + bias[cg]);
        } else if (EPI == 3) {
          Cfb[row * (long)ldC + cg] = v;
        }
      }
    }
}

// ---------------------------------------------------------------------------
// zq_gemm (512 threads, 8 waves 2x4), BK=64 ping-pong: z fp16 output.
// z[m,n] = -(1/1024)*( sum_k q^2[m,k]*iw[n,k] + q[m,k]*c2[n,k] + cc[n] )
// A-fragments squared in registers (v_pk_mul_f16). 128x128 tile, 48 KB LDS.
// ---------------------------------------------------------------------------
__global__ __launch_bounds__(512, 4) void zq_gemm(
    const _Float16* __restrict__ Q, const _Float16* __restrict__ Iw,
    const _Float16* __restrict__ C2, const float* __restrict__ cc,
    _Float16* __restrict__ Zh) {
  __shared__ _Float16 As[2][128 * 32];
  __shared__ _Float16 B1[2][128 * 32];
  __shared__ _Float16 B2[2][128 * 32];
  int x, yy;
  swizzle_xy(x, yy);
  const int n0 = x * 128;
  const int m0 = yy * 128;

  const int tid = threadIdx.x;
  const int wave = tid >> 6, lane = tid & 63;
  const int wm = wave >> 2, wn = wave & 3;
  const int quad = lane >> 4, tr = lane & 15;
  const int lrow = lane >> 2;
  const int lcol = (lane & 3) * 8;

  f4v acc[4][2];
#pragma unroll
  for (int i = 0; i < 4; ++i)
#pragma unroll
    for (int j = 0; j < 2; ++j) acc[i][j] = (f4v){0.f, 0.f, 0.f, 0.f};

  for (int k0 = 0; k0 < 512; k0 += 64) {
    __syncthreads();
    {  // per wave: one 16-row chunk of each of A, B1, B2, in both k-halves
      const long ga = (long)(m0 + wave * 16 + lrow) * 512 + k0 + lcol;
      async_copy16(Q + ga, &As[0][wave * 512]);
      async_copy16(Q + ga + 32, &As[1][wave * 512]);
      const long gb = (long)(n0 + wave * 16 + lrow) * 512 + k0 + lcol;
      async_copy16(Iw + gb, &B1[0][wave * 512]);
      async_copy16(Iw + gb + 32, &B1[1][wave * 512]);
      async_copy16(C2 + gb, &B2[0][wave * 512]);
      async_copy16(C2 + gb + 32, &B2[1][wave * 512]);
    }
    __syncthreads();

#pragma unroll
    for (int h = 0; h < 2; ++h) {
      h8v af[4], af2[4], b1[2], b2[2];
#pragma unroll
      for (int i = 0; i < 4; ++i) {
        af[i] = *(const h8v*)&As[h][(wm * 64 + i * 16 + tr) * 32 + quad * 8];
        af2[i] = af[i] * af[i];
      }
#pragma unroll
      for (int j = 0; j < 2; ++j) {
        b1[j] = *(const h8v*)&B1[h][(wn * 32 + j * 16 + tr) * 32 + quad * 8];
        b2[j] = *(const h8v*)&B2[h][(wn * 32 + j * 16 + tr) * 32 + quad * 8];
      }
#pragma unroll
      for (int i = 0; i < 4; ++i)
#pragma unroll
        for (int j = 0; j < 2; ++j) {
          acc[i][j] = __builtin_amdgcn_mfma_f32_16x16x32_f16(af2[i], b1[j], acc[i][j], 0, 0, 0);
          acc[i][j] = __builtin_amdgcn_mfma_f32_16x16x32_f16(af[i], b2[j], acc[i][j], 0, 0, 0);
        }
    }
  }

  constexpr float zs = -0.0009765625f;  // -(0.5/512)
#pragma unroll
  for (int i = 0; i < 4; ++i)
#pragma unroll
    for (int j = 0; j < 2; ++j) {
      const int rbase = m0 + wm * 64 + i * 16 + quad * 4;
      const int cg = n0 + wn * 32 + j * 16 + tr;
      const float ccv = cc[cg];
#pragma unroll
      for (int r = 0; r < 4; ++r)
        Zh[(long)(rbase + r) * 512 + cg] = (_Float16)((acc[i][j][r] + ccv) * zs);
    }
}

// ---------------------------------------------------------------------------
// softmax over R=512: read z fp16, write Fss fp16. One wave per row.
// ---------------------------------------------------------------------------
__global__ __launch_bounds__(256) void softmax_h(const _Float16* __restrict__ Zh,
                                                 _Float16* __restrict__ F) {
  const int wave = threadIdx.x >> 6;
  const int lane = threadIdx.x & 63;
  const long row = (long)blockIdx.x * 4 + wave;
  h8v zv = *(const h8v*)&Zh[row * Rr + lane * 8];
  float v[8];
#pragma unroll
  for (int i = 0; i < 8; ++i) v[i] = (float)zv[i];
  float m = v[0];
#pragma unroll
  for (int i = 1; i < 8; ++i) m = fmaxf(m, v[i]);
#pragma unroll
  for (int s = 32; s > 0; s >>= 1) m = fmaxf(m, __shfl_xor(m, s, 64));
  float sum = 0.f;
#pragma unroll
  for (int i = 0; i < 8; ++i) {
    v[i] = __expf(v[i] - m);
    sum += v[i];
  }
#pragma unroll
  for (int s = 32; s > 0; s >>= 1) sum += __shfl_xor(sum, s, 64);
  const float inv = 1.0f / sum;
  h8v o;
#pragma unroll
  for (int i = 0; i < 8; ++i) o[i] = (_Float16)(v[i] * inv);
  *(h8v*)&F[row * Rr + lane * 8] = o;
}

// ---------------------------------------------------------------------------
extern "C" void kernel_launch(void* const* d_in, const int* in_sizes, int n_in,
                              void* d_out, int out_size, void* d_ws, size_t ws_size,
                              hipStream_t stream) {
  const float* query   = (const float*)d_in[0];
  const float* Wq      = (const float*)d_in[1];
  const float* bq      = (const float*)d_in[2];
  const float* Wc      = (const float*)d_in[3];
  const float* bc      = (const float*)d_in[4];
  const float* centers = (const float*)d_in[5];
  const float* widths  = (const float*)d_in[6];
  float* out = (float*)d_out;

  char* base = (char*)d_ws;
  auto alloc = [&](size_t bytes) {
    char* p = base;
    base += (bytes + 255) & ~(size_t)255;
    return p;
  };
  _Float16* qs  = (_Float16*)alloc((size_t)M1 * Dd * 2);      // 16.8 MB
  _Float16* qt  = (_Float16*)alloc((size_t)M1 * Dd * 2);      // 16.8 MB (B,D,L)
  _Float16* q16 = (_Float16*)alloc((size_t)M1 * Dd * 2);      // 16.8 MB
  _Float16* zh  = (_Float16*)alloc((size_t)M1 * Rr * 2);      // 16.8 MB (z fp16)
  _Float16* fs  = (_Float16*)alloc((size_t)M1 * Rr * 2);      // 16.8 MB
  _Float16* wq  = (_Float16*)alloc((size_t)Dd * Dd * 2);
  _Float16* wc  = (_Float16*)alloc((size_t)Rr * Ls * 2);
  _Float16* iwh = (_Float16*)alloc((size_t)Rr * Dd * 2);
  _Float16* c2h = (_Float16*)alloc((size_t)Rr * Dd * 2);
  float*    cc  = (float*)alloc((size_t)Rr * 4);
  float*    cqp = (float*)alloc((size_t)2 * Bb * Dd * Rr * 4); // 16.8 MB partials
  _Float16* cq  = (_Float16*)alloc((size_t)Bb * Dd * Rr * 2);  // 4.2 MB

  // all conversions + fuzzy-param precompute, one launch
  prep_all<<<3456, 256, 0, stream>>>(query, qs, qt, Wq, wq, Wc, wc,
                                     centers, widths, iwh, c2h, cc);

  // q-GEMM: q16 = fp16(query @ Wq^T + bq)   grid (4,128) = 512 blocks
  gemm_h<4, 2><<<dim3(Dd / 128, M1 / 128, 1), 512, 0, stream>>>(
      qs, wq, bq, nullptr, q16, Dd, Dd, Dd, Dd, 0, 0, 0, 0);

  // z-GEMM (in-register squared A), fp16 z out   grid (4,128)
  zq_gemm<<<dim3(Rr / 128, M1 / 128, 1), 512, 0, stream>>>(q16, iwh, c2h, cc, zh);

  // softmax -> Fss fp16
  softmax_h<<<M1 / 4, 256, 0, stream>>>(zh, fs);

  // conq split-K=2, plain stores to private partial slices:
  // cqp[s][(b,d), r] = qt[(b,d), s*1024:(s+1)*1024] . Wc[r, same]
  gemm_h<2, 3><<<dim3(Rr / 128, (Bb * Dd) / 64, 2), 512, 0, stream>>>(
      qt, wc, nullptr, cqp, nullptr, 1024, Ls, Ls, Rr, 1024,
      0, 0, (long)Bb * Dd * Rr);
  reduce_cq<<<(Bb * Dd * Rr / 4 + 255) / 256, 256, 0, stream>>>(
      cqp, cqp + (long)Bb * Dd * Rr, bc, cq, Bb * Dd * Rr / 4);

  // out-GEMM: out[b] = Fss[b] @ cq[b]^T   grid (4,16,8)
  gemm_h<4, 3><<<dim3(Dd / 128, Ls / 128, Bb), 512, 0, stream>>>(
      fs, cq, nullptr, out, nullptr, Rr, Rr, Rr, Dd, 0,
      (long)Ls * Rr, (long)Dd * Rr, (long)Ls * Dd);
}